// Round 13
// baseline (214.885 us; speedup 1.0000x reference)
//
#include <hip/hip_runtime.h>

#define NA 900
#define NP 13
#define NCAM 6
#define NL 4
#define NG 8
#define NC 256
#define TOTALHW 14960
#define NW 8                         // waves per block
#define NSL (NP * NCAM)              // 78 samples per level per anchor
#define FEAT_ELEMS (NCAM * TOTALHW * NC)   // 22,978,560

__device__ __forceinline__ float bfu(unsigned short u) {
    union { unsigned int i; float f; } x;
    x.i = ((unsigned int)u) << 16;
    return x.f;
}

// ---- prologue: f32 -> bf16 (RNE) streaming conversion
__global__ __launch_bounds__(256) void cvt_kernel(
    const uint4* __restrict__ src, uint4* __restrict__ dst)
{
    const int n8 = FEAT_ELEMS / 8;
    for (int i = blockIdx.x * 256 + threadIdx.x; i < n8; i += gridDim.x * 256) {
        union { uint4 u; float f[4]; } a, b;
        a.u = src[2 * i];
        b.u = src[2 * i + 1];
        unsigned int w[8];
        #pragma unroll
        for (int k = 0; k < 4; ++k) {
            union { float f; unsigned int u; } x;
            x.f = a.f[k];
            w[k] = (x.u + 0x7FFFu + ((x.u >> 16) & 1u)) >> 16;
            x.f = b.f[k];
            w[4 + k] = (x.u + 0x7FFFu + ((x.u >> 16) & 1u)) >> 16;
        }
        uint4 o;
        o.x = w[0] | (w[1] << 16);
        o.y = w[2] | (w[3] << 16);
        o.z = w[4] | (w[5] << 16);
        o.w = w[6] | (w[7] << 16);
        dst[i] = o;
    }
}

// ---- per-level gather kernel: hard phase alignment via separate launches.
// Sample order cam-major (s = cam*NP + p) so the instantaneous working set
// during a phase is one camera's level slice (L2-resident for levels 1-3).
template<int L, int H, int W, int ST, bool INIT>
__global__ __launch_bounds__(512) void daf_level(
    const unsigned short* __restrict__ featb,
    const float* __restrict__ points,
    const float* __restrict__ weights,
    float* __restrict__ out)
{
    const int a    = blockIdx.x;
    const int tid  = threadIdx.x;
    const int wv   = tid >> 6;
    const int lane = tid & 63;

    __shared__ int    s_idx[NSL][4];
    __shared__ float  s_cw[NSL][4];
    __shared__ float  s_wg[NSL * NG];
    __shared__ float4 s_part[NW][64];

    // stage this level's group weights, remapped to cam-major order
    // weights layout: [A][P][CAM][L][G]
    const float* wsrc = weights + (size_t)a * NP * NCAM * NL * NG;
    for (int i = tid; i < NSL * NG; i += 512) {
        const int g   = i & (NG - 1);
        const int s   = i >> 3;          // cam-major sample id
        const int cam = s / NP;
        const int p   = s - cam * NP;
        s_wg[i] = wsrc[((p * NCAM + cam) * NL + L) * NG + g];
    }

    // build 78 sample descriptors
    if (tid < NSL) {
        const int s   = tid;
        const int cam = s / NP;
        const int p   = s - cam * NP;

        const float2 pt = *(const float2*)(points + (((size_t)a * NP + p) * NCAM + cam) * 2);
        const float x   = pt.x * (float)W - 0.5f;
        const float y   = pt.y * (float)H - 0.5f;
        const float x0f = floorf(x);
        const float y0f = floorf(y);
        const int   x0  = (int)x0f;
        const int   y0  = (int)y0f;
        const float fx  = x - x0f;
        const float fy  = y - y0f;
        const float wx[2] = {1.0f - fx, fx};
        const float wy[2] = {1.0f - fy, fy};

        const int base = cam * TOTALHW + ST;
        #pragma unroll
        for (int k = 0; k < 4; ++k) {
            const int dx = k & 1;
            const int dy = k >> 1;
            const int xi = x0 + dx;
            const int yi = y0 + dy;
            const bool valid = (xi >= 0) && (xi < W) && (yi >= 0) && (yi < H);
            const int xc = min(max(xi, 0), W - 1);
            const int yc = min(max(yi, 0), H - 1);
            s_idx[s][k] = base + yc * W + xc;
            s_cw[s][k]  = valid ? wx[dx] * wy[dy] : 0.0f;
        }
    }
    __syncthreads();

    const int g = lane >> 3;
    const ushort4* __restrict__ fb = (const ushort4*)featb;

    float4 acc = make_float4(0.f, 0.f, 0.f, 0.f);

    // 2-deep software pipeline: issue next sample's 4 row-loads before
    // consuming the current one (covers latency in low-occupancy phases)
    int s = wv;
    int4   ii;  float4 cc;  float wg = 0.f;
    ushort4 r0, r1, r2, r3;
    if (s < NSL) {
        ii = *(const int4*)s_idx[s];
        cc = *(const float4*)s_cw[s];
        wg = s_wg[s * NG + g];
        r0 = fb[(size_t)ii.x * 64 + lane];
        r1 = fb[(size_t)ii.y * 64 + lane];
        r2 = fb[(size_t)ii.z * 64 + lane];
        r3 = fb[(size_t)ii.w * 64 + lane];
    }
    while (s < NSL) {
        const int sn = s + NW;
        int4 ni; float4 nc; float nwg = 0.f;
        ushort4 n0, n1, n2, n3;
        if (sn < NSL) {
            ni  = *(const int4*)s_idx[sn];
            nc  = *(const float4*)s_cw[sn];
            nwg = s_wg[sn * NG + g];
            n0 = fb[(size_t)ni.x * 64 + lane];
            n1 = fb[(size_t)ni.y * 64 + lane];
            n2 = fb[(size_t)ni.z * 64 + lane];
            n3 = fb[(size_t)ni.w * 64 + lane];
        }
        const float c0 = cc.x * wg, c1 = cc.y * wg;
        const float c2 = cc.z * wg, c3 = cc.w * wg;

        acc.x += bfu(r0.x) * c0 + bfu(r1.x) * c1 + bfu(r2.x) * c2 + bfu(r3.x) * c3;
        acc.y += bfu(r0.y) * c0 + bfu(r1.y) * c1 + bfu(r2.y) * c2 + bfu(r3.y) * c3;
        acc.z += bfu(r0.z) * c0 + bfu(r1.z) * c1 + bfu(r2.z) * c2 + bfu(r3.z) * c3;
        acc.w += bfu(r0.w) * c0 + bfu(r1.w) * c1 + bfu(r2.w) * c2 + bfu(r3.w) * c3;

        r0 = n0; r1 = n1; r2 = n2; r3 = n3;
        cc = nc; wg = nwg;
        s = sn;
    }

    s_part[wv][lane] = acc;
    __syncthreads();

    if (tid < 64) {
        float4 r = s_part[0][lane];
        #pragma unroll
        for (int k = 1; k < NW; ++k) {
            const float4 p = s_part[k][lane];
            r.x += p.x; r.y += p.y; r.z += p.z; r.w += p.w;
        }
        float4* po = (float4*)out + (size_t)a * 64 + lane;
        if (INIT) {
            *po = r;
        } else {
            float4 t = *po;
            t.x += r.x; t.y += r.y; t.z += r.z; t.w += r.w;
            *po = t;
        }
    }
}

// ---- fallback: proven f32 single-kernel path (if ws too small)
#define NPC (NP * NCAM)
#define NS (NPC * NL)
__device__ __constant__ int c_h[NL]  = {64, 32, 16, 8};
__device__ __constant__ int c_w[NL]  = {176, 88, 44, 22};
__device__ __constant__ int c_st[NL] = {0, 11264, 14080, 14784};

__global__ __launch_bounds__(512) void daf_f32_kernel(
    const float* __restrict__ feature,
    const float* __restrict__ points,
    const float* __restrict__ weights,
    float* __restrict__ out)
{
    const int a    = blockIdx.x;
    const int tid  = threadIdx.x;
    const int wv   = tid >> 6;
    const int lane = tid & 63;

    __shared__ int    s_idx[NS][4];
    __shared__ float  s_cw[NS][4];
    __shared__ float  s_wg[NS * NG];
    __shared__ float4 s_part[NW][64];

    const float* wsrc = weights + (size_t)a * NS * NG;
    for (int i = tid; i < NS * NG; i += 512) {
        const int g  = i & (NG - 1);
        const int s  = i >> 3;
        const int l  = s / NPC;
        const int pc = s - l * NPC;
        s_wg[i] = wsrc[(pc * NL + l) * NG + g];
    }

    if (tid < NS) {
        const int s   = tid;
        const int l   = s / NPC;
        const int pc  = s - l * NPC;
        const int cam = pc % NCAM;
        const int p   = pc / NCAM;

        const float2 pt = *(const float2*)(points + (((size_t)a * NP + p) * NCAM + cam) * 2);
        const int h  = c_h[l];
        const int w  = c_w[l];
        const int st = c_st[l];

        const float x   = pt.x * (float)w - 0.5f;
        const float y   = pt.y * (float)h - 0.5f;
        const float x0f = floorf(x);
        const float y0f = floorf(y);
        const int   x0  = (int)x0f;
        const int   y0  = (int)y0f;
        const float fx  = x - x0f;
        const float fy  = y - y0f;
        const float wx[2] = {1.0f - fx, fx};
        const float wy[2] = {1.0f - fy, fy};

        const int base = cam * TOTALHW + st;
        #pragma unroll
        for (int k = 0; k < 4; ++k) {
            const int dx = k & 1;
            const int dy = k >> 1;
            const int xi = x0 + dx;
            const int yi = y0 + dy;
            const bool valid = (xi >= 0) && (xi < w) && (yi >= 0) && (yi < h);
            const int xc = min(max(xi, 0), w - 1);
            const int yc = min(max(yi, 0), h - 1);
            s_idx[s][k] = base + yc * w + xc;
            s_cw[s][k]  = valid ? wx[dx] * wy[dy] : 0.0f;
        }
    }
    __syncthreads();

    const int g = lane >> 3;
    const float4* __restrict__ f4 = (const float4*)feature;

    float4 acc = make_float4(0.f, 0.f, 0.f, 0.f);
    for (int s = wv; s < NS; s += NW) {
        const float wg = s_wg[s * NG + g];
        const int   i0 = s_idx[s][0], i1 = s_idx[s][1], i2 = s_idx[s][2], i3 = s_idx[s][3];
        const float c0 = s_cw[s][0] * wg, c1 = s_cw[s][1] * wg;
        const float c2 = s_cw[s][2] * wg, c3 = s_cw[s][3] * wg;

        const float4 v0 = f4[(size_t)i0 * 64 + lane];
        const float4 v1 = f4[(size_t)i1 * 64 + lane];
        const float4 v2 = f4[(size_t)i2 * 64 + lane];
        const float4 v3 = f4[(size_t)i3 * 64 + lane];

        acc.x += v0.x * c0 + v1.x * c1 + v2.x * c2 + v3.x * c3;
        acc.y += v0.y * c0 + v1.y * c1 + v2.y * c2 + v3.y * c3;
        acc.z += v0.z * c0 + v1.z * c1 + v2.z * c2 + v3.z * c3;
        acc.w += v0.w * c0 + v1.w * c1 + v2.w * c2 + v3.w * c3;
    }

    s_part[wv][lane] = acc;
    __syncthreads();

    if (tid < 64) {
        float4 r = s_part[0][lane];
        #pragma unroll
        for (int k = 1; k < NW; ++k) {
            const float4 p = s_part[k][lane];
            r.x += p.x; r.y += p.y; r.z += p.z; r.w += p.w;
        }
        ((float4*)out)[(size_t)a * 64 + lane] = r;
    }
}

extern "C" void kernel_launch(void* const* d_in, const int* in_sizes, int n_in,
                              void* d_out, int out_size, void* d_ws, size_t ws_size,
                              hipStream_t stream) {
    const float* feature = (const float*)d_in[0];
    const float* points  = (const float*)d_in[3];
    const float* weights = (const float*)d_in[4];
    float*       out     = (float*)d_out;

    const size_t need = (size_t)FEAT_ELEMS * sizeof(unsigned short);  // ~46 MB
    if (ws_size >= need && d_ws != nullptr) {
        unsigned short* featb = (unsigned short*)d_ws;
        cvt_kernel<<<2048, 256, 0, stream>>>((const uint4*)feature, (uint4*)featb);
        // hard level-phase alignment: small levels first, L0 (largest) last
        daf_level<3,  8,  22, 14784, true ><<<NA, 512, 0, stream>>>(featb, points, weights, out);
        daf_level<2, 16,  44, 14080, false><<<NA, 512, 0, stream>>>(featb, points, weights, out);
        daf_level<1, 32,  88, 11264, false><<<NA, 512, 0, stream>>>(featb, points, weights, out);
        daf_level<0, 64, 176,     0, false><<<NA, 512, 0, stream>>>(featb, points, weights, out);
    } else {
        daf_f32_kernel<<<NA, 512, 0, stream>>>(feature, points, weights, out);
    }
}

// Round 15
// 198.980 us; speedup vs baseline: 1.0799x; 1.0799x over previous
//
#include <hip/hip_runtime.h>

#define NA 900
#define NP 13
#define NCAM 6
#define NL 4
#define NG 8
#define NC 256
#define TOTALHW 14960
#define NPC (NP * NCAM)      // 78 point-cam pairs
#define NS (NPC * NL)        // 312 samples per anchor
#define NW 8                 // waves per block
#define FEAT_ELEMS (NCAM * TOTALHW * NC)   // 22,978,560

typedef unsigned int u32x4 __attribute__((ext_vector_type(4)));

// static level metadata (LEVEL_SHAPES is compile-time constant in the reference)
__device__ __constant__ int c_h[NL]  = {64, 32, 16, 8};
__device__ __constant__ int c_w[NL]  = {176, 88, 44, 22};
__device__ __constant__ int c_st[NL] = {0, 11264, 14080, 14784};

__device__ __forceinline__ float bfu(unsigned short u) {
    union { unsigned int i; float f; } x;
    x.i = ((unsigned int)u) << 16;
    return x.f;
}

// ---- prologue: f32 -> bf16 (RNE). Nontemporal SOURCE loads (src is
// never re-read; keep it out of L2/L3 so featb stays resident for the
// gather). Destination stores stay cached on purpose.
__global__ __launch_bounds__(256) void cvt_kernel(
    const u32x4* __restrict__ src, u32x4* __restrict__ dst)
{
    const int n8 = FEAT_ELEMS / 8;
    for (int i = blockIdx.x * 256 + threadIdx.x; i < n8; i += gridDim.x * 256) {
        u32x4 a = __builtin_nontemporal_load(src + 2 * i);
        u32x4 b = __builtin_nontemporal_load(src + 2 * i + 1);
        unsigned int w[8];
        #pragma unroll
        for (int k = 0; k < 4; ++k) {
            w[k]     = (a[k] + 0x7FFFu + ((a[k] >> 16) & 1u)) >> 16;
            w[4 + k] = (b[k] + 0x7FFFu + ((b[k] >> 16) & 1u)) >> 16;
        }
        u32x4 o;
        o[0] = w[0] | (w[1] << 16);
        o[1] = w[2] | (w[3] << 16);
        o[2] = w[4] | (w[5] << 16);
        o[3] = w[6] | (w[7] << 16);
        dst[i] = o;
    }
}

// ---- main gather kernel (R6-proven structure): level-major soft ordering,
// single launch, 8 waves/block, ushort4 row fragments.
__global__ __launch_bounds__(512) void daf_bf16_kernel(
    const unsigned short* __restrict__ featb,
    const float* __restrict__ points,
    const float* __restrict__ weights,
    float* __restrict__ out)
{
    const int a    = blockIdx.x;
    const int tid  = threadIdx.x;
    const int wv   = tid >> 6;   // wave 0..7
    const int lane = tid & 63;

    // descriptors stored LEVEL-MAJOR: s = l * NPC + pc
    __shared__ int    s_idx[NS][4];
    __shared__ float  s_cw[NS][4];
    __shared__ float  s_wg[NS * NG];
    __shared__ float4 s_part[NW][64];

    // stage per-anchor group weights, remapped to level-major order
    const float* wsrc = weights + (size_t)a * NS * NG;
    for (int i = tid; i < NS * NG; i += 512) {
        const int g  = i & (NG - 1);
        const int s  = i >> 3;          // level-major sample id
        const int l  = s / NPC;
        const int pc = s - l * NPC;
        s_wg[i] = wsrc[(pc * NL + l) * NG + g];
    }

    // build 312 sample descriptors (level-major; once per block)
    if (tid < NS) {
        const int s   = tid;
        const int l   = s / NPC;
        const int pc  = s - l * NPC;
        const int cam = pc % NCAM;
        const int p   = pc / NCAM;

        const float2 pt = *(const float2*)(points + (((size_t)a * NP + p) * NCAM + cam) * 2);
        const int h  = c_h[l];
        const int w  = c_w[l];
        const int st = c_st[l];

        const float x   = pt.x * (float)w - 0.5f;
        const float y   = pt.y * (float)h - 0.5f;
        const float x0f = floorf(x);
        const float y0f = floorf(y);
        const int   x0  = (int)x0f;
        const int   y0  = (int)y0f;
        const float fx  = x - x0f;
        const float fy  = y - y0f;
        const float wx[2] = {1.0f - fx, fx};
        const float wy[2] = {1.0f - fy, fy};

        const int base = cam * TOTALHW + st;
        #pragma unroll
        for (int k = 0; k < 4; ++k) {
            const int dx = k & 1;
            const int dy = k >> 1;
            const int xi = x0 + dx;
            const int yi = y0 + dy;
            const bool valid = (xi >= 0) && (xi < w) && (yi >= 0) && (yi < h);
            const int xc = min(max(xi, 0), w - 1);
            const int yc = min(max(yi, 0), h - 1);
            s_idx[s][k] = base + yc * w + xc;
            s_cw[s][k]  = valid ? wx[dx] * wy[dy] : 0.0f;
        }
    }
    __syncthreads();

    // gather + accumulate, level-major. Each lane owns channels [lane*4, lane*4+4)
    const int g = lane >> 3;                       // (lane*4)/32
    const ushort4* __restrict__ fb = (const ushort4*)featb;

    float4 acc = make_float4(0.f, 0.f, 0.f, 0.f);
    #pragma unroll 2
    for (int s = wv; s < NS; s += NW) {
        const float wg = s_wg[s * NG + g];
        const int   i0 = s_idx[s][0], i1 = s_idx[s][1], i2 = s_idx[s][2], i3 = s_idx[s][3];
        const float c0 = s_cw[s][0] * wg, c1 = s_cw[s][1] * wg;
        const float c2 = s_cw[s][2] * wg, c3 = s_cw[s][3] * wg;

        const ushort4 r0 = fb[(size_t)i0 * 64 + lane];
        const ushort4 r1 = fb[(size_t)i1 * 64 + lane];
        const ushort4 r2 = fb[(size_t)i2 * 64 + lane];
        const ushort4 r3 = fb[(size_t)i3 * 64 + lane];

        acc.x += bfu(r0.x) * c0 + bfu(r1.x) * c1 + bfu(r2.x) * c2 + bfu(r3.x) * c3;
        acc.y += bfu(r0.y) * c0 + bfu(r1.y) * c1 + bfu(r2.y) * c2 + bfu(r3.y) * c3;
        acc.z += bfu(r0.z) * c0 + bfu(r1.z) * c1 + bfu(r2.z) * c2 + bfu(r3.z) * c3;
        acc.w += bfu(r0.w) * c0 + bfu(r1.w) * c1 + bfu(r2.w) * c2 + bfu(r3.w) * c3;
    }

    s_part[wv][lane] = acc;
    __syncthreads();

    if (tid < 64) {
        float4 r = s_part[0][lane];
        #pragma unroll
        for (int k = 1; k < NW; ++k) {
            const float4 p = s_part[k][lane];
            r.x += p.x; r.y += p.y; r.z += p.z; r.w += p.w;
        }
        ((float4*)out)[(size_t)a * 64 + lane] = r;
    }
}

// ---- fallback: proven f32 kernel (used only if ws too small)
__global__ __launch_bounds__(512) void daf_f32_kernel(
    const float* __restrict__ feature,
    const float* __restrict__ points,
    const float* __restrict__ weights,
    float* __restrict__ out)
{
    const int a    = blockIdx.x;
    const int tid  = threadIdx.x;
    const int wv   = tid >> 6;
    const int lane = tid & 63;

    __shared__ int    s_idx[NS][4];
    __shared__ float  s_cw[NS][4];
    __shared__ float  s_wg[NS * NG];
    __shared__ float4 s_part[NW][64];

    const float* wsrc = weights + (size_t)a * NS * NG;
    for (int i = tid; i < NS * NG; i += 512) {
        const int g  = i & (NG - 1);
        const int s  = i >> 3;
        const int l  = s / NPC;
        const int pc = s - l * NPC;
        s_wg[i] = wsrc[(pc * NL + l) * NG + g];
    }

    if (tid < NS) {
        const int s   = tid;
        const int l   = s / NPC;
        const int pc  = s - l * NPC;
        const int cam = pc % NCAM;
        const int p   = pc / NCAM;

        const float2 pt = *(const float2*)(points + (((size_t)a * NP + p) * NCAM + cam) * 2);
        const int h  = c_h[l];
        const int w  = c_w[l];
        const int st = c_st[l];

        const float x   = pt.x * (float)w - 0.5f;
        const float y   = pt.y * (float)h - 0.5f;
        const float x0f = floorf(x);
        const float y0f = floorf(y);
        const int   x0  = (int)x0f;
        const int   y0  = (int)y0f;
        const float fx  = x - x0f;
        const float fy  = y - y0f;
        const float wx[2] = {1.0f - fx, fx};
        const float wy[2] = {1.0f - fy, fy};

        const int base = cam * TOTALHW + st;
        #pragma unroll
        for (int k = 0; k < 4; ++k) {
            const int dx = k & 1;
            const int dy = k >> 1;
            const int xi = x0 + dx;
            const int yi = y0 + dy;
            const bool valid = (xi >= 0) && (xi < w) && (yi >= 0) && (yi < h);
            const int xc = min(max(xi, 0), w - 1);
            const int yc = min(max(yi, 0), h - 1);
            s_idx[s][k] = base + yc * w + xc;
            s_cw[s][k]  = valid ? wx[dx] * wy[dy] : 0.0f;
        }
    }
    __syncthreads();

    const int g = lane >> 3;
    const float4* __restrict__ f4 = (const float4*)feature;

    float4 acc = make_float4(0.f, 0.f, 0.f, 0.f);
    for (int s = wv; s < NS; s += NW) {
        const float wg = s_wg[s * NG + g];
        const int   i0 = s_idx[s][0], i1 = s_idx[s][1], i2 = s_idx[s][2], i3 = s_idx[s][3];
        const float c0 = s_cw[s][0] * wg, c1 = s_cw[s][1] * wg;
        const float c2 = s_cw[s][2] * wg, c3 = s_cw[s][3] * wg;

        const float4 v0 = f4[(size_t)i0 * 64 + lane];
        const float4 v1 = f4[(size_t)i1 * 64 + lane];
        const float4 v2 = f4[(size_t)i2 * 64 + lane];
        const float4 v3 = f4[(size_t)i3 * 64 + lane];

        acc.x += v0.x * c0 + v1.x * c1 + v2.x * c2 + v3.x * c3;
        acc.y += v0.y * c0 + v1.y * c1 + v2.y * c2 + v3.y * c3;
        acc.z += v0.z * c0 + v1.z * c1 + v2.z * c2 + v3.z * c3;
        acc.w += v0.w * c0 + v1.w * c1 + v2.w * c2 + v3.w * c3;
    }

    s_part[wv][lane] = acc;
    __syncthreads();

    if (tid < 64) {
        float4 r = s_part[0][lane];
        #pragma unroll
        for (int k = 1; k < NW; ++k) {
            const float4 p = s_part[k][lane];
            r.x += p.x; r.y += p.y; r.z += p.z; r.w += p.w;
        }
        ((float4*)out)[(size_t)a * 64 + lane] = r;
    }
}

extern "C" void kernel_launch(void* const* d_in, const int* in_sizes, int n_in,
                              void* d_out, int out_size, void* d_ws, size_t ws_size,
                              hipStream_t stream) {
    const float* feature = (const float*)d_in[0];
    const float* points  = (const float*)d_in[3];
    const float* weights = (const float*)d_in[4];
    float*       out     = (float*)d_out;

    const size_t need = (size_t)FEAT_ELEMS * sizeof(unsigned short);  // ~46 MB
    if (ws_size >= need && d_ws != nullptr) {
        unsigned short* featb = (unsigned short*)d_ws;
        cvt_kernel<<<2048, 256, 0, stream>>>((const u32x4*)feature, (u32x4*)featb);
        daf_bf16_kernel<<<NA, 512, 0, stream>>>(featb, points, weights, out);
    } else {
        daf_f32_kernel<<<NA, 512, 0, stream>>>(feature, points, weights, out);
    }
}